// Round 6
// baseline (261.167 us; speedup 1.0000x reference)
//
#include <hip/hip_runtime.h>
#include <hip/hip_bf16.h>
#include <math.h>

#define HW2D 25600      // 160*160
#define NB 8
#define NC 256
#define CR 64
#define H_ 160
#define W_ 160

typedef short bf16x8 __attribute__((ext_vector_type(8)));
typedef float f32x4 __attribute__((ext_vector_type(4)));

__device__ __forceinline__ short f2bf(float f) {
    __hip_bfloat16 h = __float2bfloat16(f);   // v_cvt_pk_bf16_f32 pairs
    return *reinterpret_cast<short*>(&h);
}
__device__ __forceinline__ float bf2f(unsigned short b) {
    union { unsigned u; float f; } v; v.u = ((unsigned)b) << 16;
    return v.f;
}

// ---- pack reduce_w into MFMA A-fragment order: aPack[(s*4+m)*64+lane][8] ----
__global__ __launch_bounds__(256) void k_pack(const float* __restrict__ rw,
                                              short* __restrict__ aPack) {
    int t = blockIdx.x * 256 + threadIdx.x;   // 0..2047
    if (t >= 2048) return;
    int s = t >> 8, m = (t >> 6) & 3, lane = t & 63;
    int row = m * 16 + (lane & 15);           // output o within [0,64)
    int k0 = s * 32 + (lane >> 4) * 8;        // channel c
    short* dst = aPack + ((size_t)((s * 4 + m) * 64 + lane)) * 8;
#pragma unroll
    for (int j = 0; j < 8; ++j)
        dst[j] = f2bf(rw[row * NC + k0 + j]);
}

// ---- y0[b,o,px] = sum_c W[o,c]*x[b,c,px] via bf16 MFMA; y0 stored as bf16 ---
__global__ __launch_bounds__(256) void k_rmfma(const float* __restrict__ x,
                                               const short* __restrict__ aPack,
                                               unsigned short* __restrict__ y0) {
    int wave = __builtin_amdgcn_readfirstlane(threadIdx.x >> 6);  // SGPR wave id
    int lane = threadIdx.x & 63;
    int blk = blockIdx.x;
    int b = blk / 200;
    int pxb = (blk - b * 200) * 128 + wave * 32;   // wave-uniform (SGPR)
    int l15 = lane & 15, kg = lane >> 4;
    int laneoff = kg * 8 * HW2D + l15;             // per-lane 32-bit offset
    const float* xw = x + (size_t)b * NC * HW2D + pxb;   // SGPR base
    f32x4 acc[4][2];
    f32x4 zz = {0.f, 0.f, 0.f, 0.f};
#pragma unroll
    for (int m = 0; m < 4; ++m)
#pragma unroll
        for (int n = 0; n < 2; ++n) acc[m][n] = zz;
    const bf16x8* ap = (const bf16x8*)aPack + lane;
#pragma unroll
    for (int s = 0; s < 8; ++s) {
        bf16x8 a0 = ap[(s * 4 + 0) * 64];
        bf16x8 a1 = ap[(s * 4 + 1) * 64];
        bf16x8 a2 = ap[(s * 4 + 2) * 64];
        bf16x8 a3 = ap[(s * 4 + 3) * 64];
        const float* xs = xw + s * 32 * HW2D + laneoff;
        bf16x8 b0, b1;
#pragma unroll
        for (int j = 0; j < 8; ++j) {
            b0[j] = f2bf(xs[j * HW2D]);
            b1[j] = f2bf(xs[j * HW2D + 16]);
        }
        acc[0][0] = __builtin_amdgcn_mfma_f32_16x16x32_bf16(a0, b0, acc[0][0], 0, 0, 0);
        acc[0][1] = __builtin_amdgcn_mfma_f32_16x16x32_bf16(a0, b1, acc[0][1], 0, 0, 0);
        acc[1][0] = __builtin_amdgcn_mfma_f32_16x16x32_bf16(a1, b0, acc[1][0], 0, 0, 0);
        acc[1][1] = __builtin_amdgcn_mfma_f32_16x16x32_bf16(a1, b1, acc[1][1], 0, 0, 0);
        acc[2][0] = __builtin_amdgcn_mfma_f32_16x16x32_bf16(a2, b0, acc[2][0], 0, 0, 0);
        acc[2][1] = __builtin_amdgcn_mfma_f32_16x16x32_bf16(a2, b1, acc[2][1], 0, 0, 0);
        acc[3][0] = __builtin_amdgcn_mfma_f32_16x16x32_bf16(a3, b0, acc[3][0], 0, 0, 0);
        acc[3][1] = __builtin_amdgcn_mfma_f32_16x16x32_bf16(a3, b1, acc[3][1], 0, 0, 0);
    }
    // C/D layout: col = lane&15, row = (lane>>4)*4 + i
    unsigned short* yw = y0 + (size_t)b * CR * HW2D + pxb;   // SGPR base
#pragma unroll
    for (int m = 0; m < 4; ++m)
#pragma unroll
        for (int n = 0; n < 2; ++n)
#pragma unroll
            for (int i = 0; i < 4; ++i) {
                int o = m * 16 + kg * 4 + i;
                yw[o * HW2D + n * 16 + l15] = (unsigned short)f2bf(acc[m][n][i]);
            }
}

// ---------------- per-(b,c) sum / sumsq over HW (bf16 input) -----------------
__global__ __launch_bounds__(256) void k_stats(const unsigned short* __restrict__ y0,
                                               float* __restrict__ sum,
                                               float* __restrict__ sumsq) {
    int bc = blockIdx.x;  // b*64+c
    const unsigned short* yp = y0 + (size_t)bc * HW2D;
    float s = 0.f, sq = 0.f;
    for (int i = threadIdx.x; i < HW2D / 8; i += 256) {
        const ushort4* p = (const ushort4*)(yp + i * 8);
        ushort4 v0 = p[0], v1 = p[1];
        float f0 = bf2f(v0.x), f1 = bf2f(v0.y), f2 = bf2f(v0.z), f3 = bf2f(v0.w);
        float f4 = bf2f(v1.x), f5 = bf2f(v1.y), f6 = bf2f(v1.z), f7 = bf2f(v1.w);
        s += (f0 + f1 + f2 + f3) + (f4 + f5 + f6 + f7);
        sq = fmaf(f0, f0, sq); sq = fmaf(f1, f1, sq);
        sq = fmaf(f2, f2, sq); sq = fmaf(f3, f3, sq);
        sq = fmaf(f4, f4, sq); sq = fmaf(f5, f5, sq);
        sq = fmaf(f6, f6, sq); sq = fmaf(f7, f7, sq);
    }
#pragma unroll
    for (int off = 32; off; off >>= 1) {
        s += __shfl_xor(s, off, 64);
        sq += __shfl_xor(sq, off, 64);
    }
    __shared__ float ls[4], lq[4];
    int wid = threadIdx.x >> 6;
    if ((threadIdx.x & 63) == 0) { ls[wid] = s; lq[wid] = sq; }
    __syncthreads();
    if (threadIdx.x == 0) {
        sum[bc]   = ls[0] + ls[1] + ls[2] + ls[3];
        sumsq[bc] = lq[0] + lq[1] + lq[2] + lq[3];
    }
}

// ---------------- GN finalize + gate MLP + fused weights ---------------------
__global__ __launch_bounds__(512) void k_gate(const float* __restrict__ sum,
                                              const float* __restrict__ sumsq,
                                              const float* __restrict__ gn_scale,
                                              const float* __restrict__ gn_bias,
                                              const float* __restrict__ w1,
                                              const float* __restrict__ b1,
                                              const float* __restrict__ w2,
                                              const float* __restrict__ b2,
                                              const float* __restrict__ fw,
                                              float* __restrict__ sA,
                                              float* __restrict__ sB,
                                              float* __restrict__ wef) {
    int t = threadIdx.x;          // 0..511 = b*64+c
    int b = t >> 6, c = t & 63;
    __shared__ float sh_sum[512], sh_sq[512], sh_p[512], sh_h[128];
    float s = sum[t], sq = sumsq[t];
    sh_sum[t] = s;
    sh_sq[t] = sq;
    __syncthreads();
    int base = (t & ~7);
    float gs = 0.f, gq = 0.f;
#pragma unroll
    for (int i = 0; i < 8; ++i) { gs += sh_sum[base + i]; gq += sh_sq[base + i]; }
    const float invN = 1.0f / (8.0f * HW2D);
    float mean = gs * invN;
    float var = gq * invN - mean * mean;
    float rstd = rsqrtf(var + 1e-5f);
    float A = rstd * gn_scale[c];
    float Bv = gn_bias[c] - mean * A;
    sA[t] = A;
    sB[t] = Bv;
    float chmean = s * (1.0f / HW2D);
    sh_p[t] = chmean * A + Bv;
    __syncthreads();
    if (t < 128) {
        int bb = t >> 4, j = t & 15;
        float h = b1[j];
        for (int i = 0; i < 64; ++i) h = fmaf(sh_p[bb * 64 + i], w1[j * 64 + i], h);
        sh_h[t] = fmaxf(h, 0.f);
    }
    __syncthreads();
    float gacc = b2[c];
#pragma unroll
    for (int j = 0; j < 16; ++j) gacc = fmaf(sh_h[b * 16 + j], w2[c * 16 + j], gacc);
    float gamma = 1.0f / (1.0f + expf(-gacc));
    wef[t] = fw[c] + gamma * fw[CR + c];
}

// ---- fused tail v2: per-wave stencil (16 ch each) -> combine -> apply -------
// tile: 16 cols x 8 rows per block; grid (10,20,8) = 1600 blocks.
// Each wave owns 16 channels with a private double-buffered 10x20 LDS halo;
// NO block barriers in the channel loop (wave-lockstep + lgkmcnt guard).
// Halo col u <-> global col tw-2+u, so pixel col tw+col centers at halo col
// col+2 -> read base is +col+1 (cols col+1..col+3).  [round-5 bug: was +col]
__global__ __launch_bounds__(256) void k_tail(const unsigned short* __restrict__ y0,
                                              const float* __restrict__ x,
                                              const float* __restrict__ sA,
                                              const float* __restrict__ sB,
                                              const float* __restrict__ wef,
                                              float* __restrict__ out) {
    const int tw = blockIdx.x * 16, th = blockIdx.y * 8, b = blockIdx.z;
    __shared__ float sm[4][2][200];      // [wave][dbuf][10 rows * 20 cols]
    __shared__ float sh_part[4][128];
    __shared__ float sh_av[128];
    const int t = threadIdx.x;
    const int w = __builtin_amdgcn_readfirstlane(t >> 6);
    const int lane = t & 63;
    const unsigned short* yb = y0 + (size_t)b * CR * HW2D;
    const int c0 = w * 16;

    // staging slots: 100 x ushort2 (10 rows x 10 pairs); lane does i0=lane, i1=lane+64
    const int i0 = lane, i1 = lane + 64;
    const int r0s = i0 / 10, u0s = i0 - r0s * 10;
    const int r1s = i1 / 10, u1s = i1 - r1s * 10;
    float* smw = &sm[w][0][0];

    float st0a, st1a, st0b, st1b;
    auto stage_load = [&](int c) {
        const unsigned short* yc = yb + (size_t)c * HW2D;
        float A = sA[b * 64 + c], Bv = sB[b * 64 + c];
        auto ld = [&](int r, int u, float& o0, float& o1) {
            int gh = th + r - 1, gw0 = tw - 2 + u * 2;
            o0 = 0.f; o1 = 0.f;                 // zero-pad AFTER affine
            if ((unsigned)gh < 160u) {
                const unsigned short* rowp = yc + gh * W_;
                if ((unsigned)gw0 < 159u) {
                    ushort2 v = *(const ushort2*)(rowp + gw0);
                    o0 = fmaf(A, bf2f(v.x), Bv);
                    o1 = fmaf(A, bf2f(v.y), Bv);
                } else {
                    if ((unsigned)gw0 < 160u)       o0 = fmaf(A, bf2f(rowp[gw0]), Bv);
                    if ((unsigned)(gw0 + 1) < 160u) o1 = fmaf(A, bf2f(rowp[gw0 + 1]), Bv);
                }
            }
        };
        ld(r0s, u0s, st0a, st1a);
        if (lane < 36) ld(r1s, u1s, st0b, st1b);
    };
    auto stage_write = [&](int buf) {
        float* d = smw + buf * 200;
        d[r0s * 20 + u0s * 2]     = st0a;
        d[r0s * 20 + u0s * 2 + 1] = st1a;
        if (lane < 36) {
            d[r1s * 20 + u1s * 2]     = st0b;
            d[r1s * 20 + u1s * 2 + 1] = st1b;
        }
    };

    // pixel assignment: col = lane&15, rows r2*2 + {0,1} where r2 = lane>>4
    const int col = lane & 15, r2 = lane >> 4;
    float lacc0 = 0.f, lacc1 = 0.f;

    stage_load(c0);
    stage_write(0);
    for (int ci = 0; ci < 16; ++ci) {
        int c = c0 + ci;
        if (ci < 15) stage_load(c + 1);          // issue next-channel loads
        float wf = wef[b * 64 + c];
        // ensure prior ds_writes to current buffer are complete
        asm volatile("s_waitcnt lgkmcnt(0)" ::: "memory");
        const float* p = smw + (ci & 1) * 200 + (r2 * 2) * 20 + col + 1;
        float a00 = p[0],  a01 = p[1],  a02 = p[2];
        float a10 = p[20], a11 = p[21], a12 = p[22];
        float a20 = p[40], a21 = p[41], a22 = p[42];
        float a30 = p[60], a31 = p[61], a32 = p[62];
        // pixel 0: rows a0,a1,a2 (center a11)
        {
            float mu = (a00 + a01 + a02 + a10 + a11 + a12 + a20 + a21 + a22) * (1.f / 9.f);
            float gx = (a00 - a02 + 2.f * (a10 - a12) + a20 - a22) * 0.25f;
            float gy = (a00 - a20 + 2.f * (a01 - a21) + a02 - a22) * 0.25f;
            float ratio = fminf(fabsf(a11 - mu) / (fabsf(gx) + fabsf(gy) + 1e-4f), 2.f);
            lacc0 = fmaf(wf, 1.f - ratio, lacc0);
        }
        // pixel 1: rows a1,a2,a3 (center a21)
        {
            float mu = (a10 + a11 + a12 + a20 + a21 + a22 + a30 + a31 + a32) * (1.f / 9.f);
            float gx = (a10 - a12 + 2.f * (a20 - a22) + a30 - a32) * 0.25f;
            float gy = (a10 - a30 + 2.f * (a11 - a31) + a12 - a32) * 0.25f;
            float ratio = fminf(fabsf(a21 - mu) / (fabsf(gx) + fabsf(gy) + 1e-4f), 2.f);
            lacc1 = fmaf(wf, 1.f - ratio, lacc1);
        }
        if (ci < 15) stage_write((ci + 1) & 1);
    }
    sh_part[w][(r2 * 2) * 16 + col]     = lacc0;
    sh_part[w][(r2 * 2 + 1) * 16 + col] = lacc1;
    __syncthreads();
    if (t < 128) {
        float l = sh_part[0][t] + sh_part[1][t] + sh_part[2][t] + sh_part[3][t];
        sh_av[t] = fmaf(0.1f, 1.f / (1.f + expf(-l)), 1.f);   // 1 + 0.1*sigmoid
    }
    __syncthreads();

    // apply: 32 px4-slots x 8 channel-groups; 32 iterations of float4 r/w
    const int slot = t & 31, chg = t >> 5;
    const int row_s = slot >> 2, cg = slot & 3;
    float4 a4 = *(const float4*)&sh_av[row_s * 16 + cg * 4];
    const size_t pbase = (size_t)b * NC * HW2D + (size_t)(th + row_s) * W_ + tw + cg * 4;
#pragma unroll 4
    for (int it = 0; it < 32; ++it) {
        size_t xi = pbase + (size_t)(it * 8 + chg) * HW2D;
        float4 xv = *(const float4*)(x + xi);
        float4 ov;
        ov.x = xv.x * a4.x;
        ov.y = xv.y * a4.y;
        ov.z = xv.z * a4.z;
        ov.w = xv.w * a4.w;
        *(float4*)(out + xi) = ov;
    }
}

extern "C" void kernel_launch(void* const* d_in, const int* in_sizes, int n_in,
                              void* d_out, int out_size, void* d_ws, size_t ws_size,
                              hipStream_t stream) {
    const float* x   = (const float*)d_in[0];
    const float* rw  = (const float*)d_in[1];
    const float* gns = (const float*)d_in[2];
    const float* gnb = (const float*)d_in[3];
    const float* w1  = (const float*)d_in[4];
    const float* b1  = (const float*)d_in[5];
    const float* w2  = (const float*)d_in[6];
    const float* b2  = (const float*)d_in[7];
    const float* fw  = (const float*)d_in[8];
    float* out = (float*)d_out;

    float* ws    = (float*)d_ws;
    float* sum   = ws;                       // 512
    float* sumsq = sum + 512;
    float* sA    = sumsq + 512;
    float* sB    = sA + 512;
    float* wef   = sB + 512;
    short* aPack = (short*)(wef + 512);      // 16384 shorts (32 KB)
    unsigned short* y0 = (unsigned short*)(aPack + 16384);  // 13,107,200 ushorts

    hipLaunchKernelGGL(k_pack,  dim3(8),          dim3(256), 0, stream, rw, aPack);
    hipLaunchKernelGGL(k_rmfma, dim3(1600),       dim3(256), 0, stream, x, aPack, y0);
    hipLaunchKernelGGL(k_stats, dim3(512),        dim3(256), 0, stream, y0, sum, sumsq);
    hipLaunchKernelGGL(k_gate,  dim3(1),          dim3(512), 0, stream,
                       sum, sumsq, gns, gnb, w1, b1, w2, b2, fw, sA, sB, wef);
    hipLaunchKernelGGL(k_tail,  dim3(10, 20, 8),  dim3(256), 0, stream,
                       y0, x, sA, sB, wef, out);
}

// Round 7
// 161.612 us; speedup vs baseline: 1.6160x; 1.6160x over previous
//
#include <hip/hip_runtime.h>
#include <hip/hip_bf16.h>
#include <math.h>

#define HW2D 25600      // 160*160
#define NB 8
#define NC 256
#define CR 64
#define H_ 160
#define W_ 160

typedef short bf16x8 __attribute__((ext_vector_type(8)));
typedef float f32x4 __attribute__((ext_vector_type(4)));

__device__ __forceinline__ short f2bf(float f) {
    __hip_bfloat16 h = __float2bfloat16(f);   // v_cvt_pk_bf16_f32 pairs
    return *reinterpret_cast<short*>(&h);
}
__device__ __forceinline__ float bf2f(unsigned short b) {
    union { unsigned u; float f; } v; v.u = ((unsigned)b) << 16;
    return v.f;
}

// ---- pack reduce_w into MFMA A-fragment order: aPack[(s*4+m)*64+lane][8] ----
__global__ __launch_bounds__(256) void k_pack(const float* __restrict__ rw,
                                              short* __restrict__ aPack) {
    int t = blockIdx.x * 256 + threadIdx.x;   // 0..2047
    if (t >= 2048) return;
    int s = t >> 8, m = (t >> 6) & 3, lane = t & 63;
    int row = m * 16 + (lane & 15);           // output o within [0,64)
    int k0 = s * 32 + (lane >> 4) * 8;        // channel c
    short* dst = aPack + ((size_t)((s * 4 + m) * 64 + lane)) * 8;
#pragma unroll
    for (int j = 0; j < 8; ++j)
        dst[j] = f2bf(rw[row * NC + k0 + j]);
}

// ---- y1[b,px,o] (NHWC bf16) = sum_c W[o,c]*x[b,c,px] via MFMA -------------
// Also emits per-block GN partials: part[blk][0..63]=sum, [64..127]=sumsq,
// computed from the SAME bf16-rounded values the stencil will consume.
__global__ __launch_bounds__(256) void k_rmfma(const float* __restrict__ x,
                                               const short* __restrict__ aPack,
                                               unsigned short* __restrict__ y1,
                                               float* __restrict__ part) {
    int wave = __builtin_amdgcn_readfirstlane(threadIdx.x >> 6);  // SGPR wave id
    int lane = threadIdx.x & 63;
    int blk = blockIdx.x;
    int b = blk / 200;
    int pxb = (blk - b * 200) * 128 + wave * 32;   // wave-uniform (SGPR)
    int l15 = lane & 15, kg = lane >> 4;
    int laneoff = kg * 8 * HW2D + l15;             // per-lane 32-bit offset
    const float* xw = x + (size_t)b * NC * HW2D + pxb;   // SGPR base
    f32x4 acc[4][2];
    f32x4 zz = {0.f, 0.f, 0.f, 0.f};
#pragma unroll
    for (int m = 0; m < 4; ++m)
#pragma unroll
        for (int n = 0; n < 2; ++n) acc[m][n] = zz;
    const bf16x8* ap = (const bf16x8*)aPack + lane;
#pragma unroll
    for (int s = 0; s < 8; ++s) {
        bf16x8 a0 = ap[(s * 4 + 0) * 64];
        bf16x8 a1 = ap[(s * 4 + 1) * 64];
        bf16x8 a2 = ap[(s * 4 + 2) * 64];
        bf16x8 a3 = ap[(s * 4 + 3) * 64];
        const float* xs = xw + s * 32 * HW2D + laneoff;
        bf16x8 b0, b1;
#pragma unroll
        for (int j = 0; j < 8; ++j) {
            b0[j] = f2bf(xs[j * HW2D]);
            b1[j] = f2bf(xs[j * HW2D + 16]);
        }
        acc[0][0] = __builtin_amdgcn_mfma_f32_16x16x32_bf16(a0, b0, acc[0][0], 0, 0, 0);
        acc[0][1] = __builtin_amdgcn_mfma_f32_16x16x32_bf16(a0, b1, acc[0][1], 0, 0, 0);
        acc[1][0] = __builtin_amdgcn_mfma_f32_16x16x32_bf16(a1, b0, acc[1][0], 0, 0, 0);
        acc[1][1] = __builtin_amdgcn_mfma_f32_16x16x32_bf16(a1, b1, acc[1][1], 0, 0, 0);
        acc[2][0] = __builtin_amdgcn_mfma_f32_16x16x32_bf16(a2, b0, acc[2][0], 0, 0, 0);
        acc[2][1] = __builtin_amdgcn_mfma_f32_16x16x32_bf16(a2, b1, acc[2][1], 0, 0, 0);
        acc[3][0] = __builtin_amdgcn_mfma_f32_16x16x32_bf16(a3, b0, acc[3][0], 0, 0, 0);
        acc[3][1] = __builtin_amdgcn_mfma_f32_16x16x32_bf16(a3, b1, acc[3][1], 0, 0, 0);
    }
    // --- transpose 32px x 64ch to NHWC via wave-private LDS (pad 66) ---------
    // C/D layout: col(px) = lane&15, ch row = (lane>>4)*4 + i
    __shared__ unsigned short tr[4][32 * 66];
    __shared__ float st_s[4][64], st_q[4][64];
    unsigned short* trw = tr[wave];
#pragma unroll
    for (int m = 0; m < 4; ++m)
#pragma unroll
        for (int n = 0; n < 2; ++n)
#pragma unroll
            for (int i = 0; i < 4; i += 2) {
                unsigned short r0 = (unsigned short)f2bf(acc[m][n][i]);
                unsigned short r1 = (unsigned short)f2bf(acc[m][n][i + 1]);
                unsigned v = (unsigned)r0 | ((unsigned)r1 << 16);
                int o = m * 16 + kg * 4 + i;              // even
                *(unsigned*)&trw[(n * 16 + l15) * 66 + o] = v;
            }
    // readback channel-major + coalesced NHWC stores + stats accumulation
    float cs[8], cq[8];
#pragma unroll
    for (int k = 0; k < 8; ++k) { cs[k] = 0.f; cq[k] = 0.f; }
    unsigned short* yg = y1 + ((size_t)b * HW2D + pxb) * 64;
    const int e = lane & 7, a = lane >> 3;
#pragma unroll
    for (int j = 0; j < 4; ++j) {
        int p = j * 8 + a;
        int dbase = p * 66 + e * 8;                       // even ushort idx
        unsigned q0 = *(const unsigned*)&trw[dbase];
        unsigned q1 = *(const unsigned*)&trw[dbase + 2];
        unsigned q2 = *(const unsigned*)&trw[dbase + 4];
        unsigned q3 = *(const unsigned*)&trw[dbase + 6];
        uint4 vv; vv.x = q0; vv.y = q1; vv.z = q2; vv.w = q3;
        *(uint4*)(yg + (size_t)p * 64 + e * 8) = vv;
        float f0 = bf2f((unsigned short)(q0 & 0xffff)), f1 = bf2f((unsigned short)(q0 >> 16));
        float f2 = bf2f((unsigned short)(q1 & 0xffff)), f3 = bf2f((unsigned short)(q1 >> 16));
        float f4 = bf2f((unsigned short)(q2 & 0xffff)), f5 = bf2f((unsigned short)(q2 >> 16));
        float f6 = bf2f((unsigned short)(q3 & 0xffff)), f7 = bf2f((unsigned short)(q3 >> 16));
        cs[0] += f0; cq[0] = fmaf(f0, f0, cq[0]);
        cs[1] += f1; cq[1] = fmaf(f1, f1, cq[1]);
        cs[2] += f2; cq[2] = fmaf(f2, f2, cq[2]);
        cs[3] += f3; cq[3] = fmaf(f3, f3, cq[3]);
        cs[4] += f4; cq[4] = fmaf(f4, f4, cq[4]);
        cs[5] += f5; cq[5] = fmaf(f5, f5, cq[5]);
        cs[6] += f6; cq[6] = fmaf(f6, f6, cq[6]);
        cs[7] += f7; cq[7] = fmaf(f7, f7, cq[7]);
    }
    // reduce over the 8 'a' groups (lanes differing in bits 3..5)
#pragma unroll
    for (int k = 0; k < 8; ++k) {
#pragma unroll
        for (int off = 8; off < 64; off <<= 1) {
            cs[k] += __shfl_xor(cs[k], off, 64);
            cq[k] += __shfl_xor(cq[k], off, 64);
        }
    }
    if (a == 0) {   // lanes 0..7: channel block 8*e..8*e+7
#pragma unroll
        for (int k = 0; k < 8; ++k) {
            st_s[wave][e * 8 + k] = cs[k];
            st_q[wave][e * 8 + k] = cq[k];
        }
    }
    __syncthreads();
    int tt = threadIdx.x;
    if (tt < 64)
        part[(size_t)blk * 128 + tt] = st_s[0][tt] + st_s[1][tt] + st_s[2][tt] + st_s[3][tt];
    else if (tt < 128)
        part[(size_t)blk * 128 + tt] =
            st_q[0][tt - 64] + st_q[1][tt - 64] + st_q[2][tt - 64] + st_q[3][tt - 64];
}

// ---------------- GN finalize + gate MLP + fused weights ---------------------
__global__ __launch_bounds__(512) void k_gate(const float* __restrict__ part,
                                              const float* __restrict__ gn_scale,
                                              const float* __restrict__ gn_bias,
                                              const float* __restrict__ w1,
                                              const float* __restrict__ b1,
                                              const float* __restrict__ w2,
                                              const float* __restrict__ b2,
                                              const float* __restrict__ fw,
                                              float* __restrict__ sA,
                                              float* __restrict__ sB,
                                              float* __restrict__ wef) {
    int t = threadIdx.x;          // 0..511 = b*64+c
    int b = t >> 6, c = t & 63;
    __shared__ float sh_sum[512], sh_sq[512], sh_p[512], sh_h[128];
    float s = 0.f, sq = 0.f;
    const float* pb = part + (size_t)b * 200 * 128;
    for (int k = 0; k < 200; ++k) {
        s  += pb[k * 128 + c];
        sq += pb[k * 128 + 64 + c];
    }
    sh_sum[t] = s;
    sh_sq[t] = sq;
    __syncthreads();
    int base = (t & ~7);
    float gs = 0.f, gq = 0.f;
#pragma unroll
    for (int i = 0; i < 8; ++i) { gs += sh_sum[base + i]; gq += sh_sq[base + i]; }
    const float invN = 1.0f / (8.0f * HW2D);
    float mean = gs * invN;
    float var = gq * invN - mean * mean;
    float rstd = rsqrtf(var + 1e-5f);
    float A = rstd * gn_scale[c];
    float Bv = gn_bias[c] - mean * A;
    sA[t] = A;
    sB[t] = Bv;
    float chmean = s * (1.0f / HW2D);
    sh_p[t] = chmean * A + Bv;
    __syncthreads();
    if (t < 128) {
        int bb = t >> 4, j = t & 15;
        float h = b1[j];
        for (int i = 0; i < 64; ++i) h = fmaf(sh_p[bb * 64 + i], w1[j * 64 + i], h);
        sh_h[t] = fmaxf(h, 0.f);
    }
    __syncthreads();
    float gacc = b2[c];
#pragma unroll
    for (int j = 0; j < 16; ++j) gacc = fmaf(sh_h[b * 16 + j], w2[c * 16 + j], gacc);
    float gamma = 1.0f / (1.0f + expf(-gacc));
    wef[t] = fw[c] + gamma * fw[CR + c];
}

// ---- stencil on NHWC raw y1, affine folded with exact border corrections ----
// tile 16x4 px; halo 6x18 px, all 64 ch staged once (pad 66 ushorts/px).
// Each wave computes 16 channels for all 64 px. abuf <- 1 + 0.1*sigmoid(logit)
__global__ __launch_bounds__(256) void k_sten(const unsigned short* __restrict__ y1,
                                              const float* __restrict__ sA,
                                              const float* __restrict__ sB,
                                              const float* __restrict__ wef,
                                              float* __restrict__ abuf) {
    const int tw = blockIdx.x * 16, th = blockIdx.y * 4, b = blockIdx.z;
    __shared__ unsigned short hal[108 * 66];   // 6 rows x 18 cols, px-major
    __shared__ float sh_part[4][64];
    const int t = threadIdx.x;
    const int w = __builtin_amdgcn_readfirstlane(t >> 6);
    const int lane = t & 63;
    const unsigned short* yb = y1 + (size_t)b * HW2D * 64;

#pragma unroll
    for (int it = 0; it < 4; ++it) {
        int i = t + it * 256;
        if (i < 864) {                         // 108 px * 8 chunks of 16B
            int pxi = i >> 3, c8 = (i & 7) * 8;
            int r = pxi / 18, u = pxi - r * 18;
            int gh = th + r - 1, gw = tw + u - 1;
            uint4 v; v.x = 0u; v.y = 0u; v.z = 0u; v.w = 0u;
            if ((unsigned)gh < 160u && (unsigned)gw < 160u)
                v = *(const uint4*)(yb + ((size_t)(gh * W_ + gw)) * 64 + c8);
            int d = pxi * 66 + c8;             // even -> 4B aligned
            *(unsigned*)&hal[d]     = v.x;
            *(unsigned*)&hal[d + 2] = v.y;
            *(unsigned*)&hal[d + 4] = v.z;
            *(unsigned*)&hal[d + 6] = v.w;
        }
    }
    __syncthreads();

    const int col = lane & 15, prow = lane >> 4;      // px (th+prow, tw+col)
    const int gh = th + prow, gw = tw + col;
    const int top = (gh == 0), bot = (gh == 159), lef = (gw == 0), rig = (gw == 159);
    // zero-pad-after-affine corrections (exact; all zero in interior)
    const float n9  = (float)(3 * (top + bot) + 3 * (lef + rig) -
                              (top + bot) * (lef + rig)) * (1.f / 9.f);
    const float sOx = (float)(lef - rig) * (float)(4 - top - bot) * 0.25f;
    const float sOy = (float)(top - bot) * (float)(4 - lef - rig) * 0.25f;
    const int p0 = prow * 18 + col;                   // window top-left halo px
    const int bc = b * 64;
    const int c0 = w * 16;
    float logit = 0.f;
#pragma unroll
    for (int cp = 0; cp < 8; ++cp) {
        int c = c0 + cp * 2;
        unsigned u00 = *(const unsigned*)&hal[(p0     ) * 66 + c];
        unsigned u01 = *(const unsigned*)&hal[(p0 +  1) * 66 + c];
        unsigned u02 = *(const unsigned*)&hal[(p0 +  2) * 66 + c];
        unsigned u10 = *(const unsigned*)&hal[(p0 + 18) * 66 + c];
        unsigned u11 = *(const unsigned*)&hal[(p0 + 19) * 66 + c];
        unsigned u12 = *(const unsigned*)&hal[(p0 + 20) * 66 + c];
        unsigned u20 = *(const unsigned*)&hal[(p0 + 36) * 66 + c];
        unsigned u21 = *(const unsigned*)&hal[(p0 + 37) * 66 + c];
        unsigned u22 = *(const unsigned*)&hal[(p0 + 38) * 66 + c];
        float A0 = sA[bc + c],     B0 = sB[bc + c],     wf0 = wef[bc + c];
        float A1 = sA[bc + c + 1], B1 = sB[bc + c + 1], wf1 = wef[bc + c + 1];
        {   // channel c (low halves)
            float v00 = bf2f((unsigned short)u00), v01 = bf2f((unsigned short)u01);
            float v02 = bf2f((unsigned short)u02), v10 = bf2f((unsigned short)u10);
            float v11 = bf2f((unsigned short)u11), v12 = bf2f((unsigned short)u12);
            float v20 = bf2f((unsigned short)u20), v21 = bf2f((unsigned short)u21);
            float v22 = bf2f((unsigned short)u22);
            float S = (v00 + v01 + v02) + (v10 + v11 + v12) + (v20 + v21 + v22);
            float gxr = (v00 - v02 + 2.f * (v10 - v12) + v20 - v22) * 0.25f;
            float gyr = (v00 - v20 + 2.f * (v01 - v21) + v02 - v22) * 0.25f;
            float dev = fmaf(A0, v11 - S * (1.f / 9.f), B0 * n9);
            float gx  = fmaf(A0, gxr, -B0 * sOx);
            float gy  = fmaf(A0, gyr, -B0 * sOy);
            float ratio = fminf(fabsf(dev) / (fabsf(gx) + fabsf(gy) + 1e-4f), 2.f);
            logit = fmaf(wf0, 1.f - ratio, logit);
        }
        {   // channel c+1 (high halves)
            float v00 = bf2f((unsigned short)(u00 >> 16)), v01 = bf2f((unsigned short)(u01 >> 16));
            float v02 = bf2f((unsigned short)(u02 >> 16)), v10 = bf2f((unsigned short)(u10 >> 16));
            float v11 = bf2f((unsigned short)(u11 >> 16)), v12 = bf2f((unsigned short)(u12 >> 16));
            float v20 = bf2f((unsigned short)(u20 >> 16)), v21 = bf2f((unsigned short)(u21 >> 16));
            float v22 = bf2f((unsigned short)(u22 >> 16));
            float S = (v00 + v01 + v02) + (v10 + v11 + v12) + (v20 + v21 + v22);
            float gxr = (v00 - v02 + 2.f * (v10 - v12) + v20 - v22) * 0.25f;
            float gyr = (v00 - v20 + 2.f * (v01 - v21) + v02 - v22) * 0.25f;
            float dev = fmaf(A1, v11 - S * (1.f / 9.f), B1 * n9);
            float gx  = fmaf(A1, gxr, -B1 * sOx);
            float gy  = fmaf(A1, gyr, -B1 * sOy);
            float ratio = fminf(fabsf(dev) / (fabsf(gx) + fabsf(gy) + 1e-4f), 2.f);
            logit = fmaf(wf1, 1.f - ratio, logit);
        }
    }
    sh_part[w][lane] = logit;
    __syncthreads();
    if (t < 64) {
        float l = sh_part[0][t] + sh_part[1][t] + sh_part[2][t] + sh_part[3][t];
        float av = fmaf(0.1f, 1.f / (1.f + expf(-l)), 1.f);
        abuf[(size_t)b * HW2D + (th + (t >> 4)) * W_ + tw + (t & 15)] = av;
    }
}

// ---------------- out = x * av, div-free grid mapping ------------------------
__global__ __launch_bounds__(256) void k_apply(const float* __restrict__ x,
                                               const float* __restrict__ abuf,
                                               float* __restrict__ out) {
    int px4 = blockIdx.x * 256 + threadIdx.x;   // 0..6399
    int c = blockIdx.y, b = blockIdx.z;
    size_t xi = ((size_t)(b * NC + c)) * (HW2D / 4) + px4;
    float4 xv = ((const float4*)x)[xi];
    float4 av = ((const float4*)abuf)[b * (HW2D / 4) + px4];
    float4 ov;
    ov.x = xv.x * av.x;
    ov.y = xv.y * av.y;
    ov.z = xv.z * av.z;
    ov.w = xv.w * av.w;
    ((float4*)out)[xi] = ov;
}

extern "C" void kernel_launch(void* const* d_in, const int* in_sizes, int n_in,
                              void* d_out, int out_size, void* d_ws, size_t ws_size,
                              hipStream_t stream) {
    const float* x   = (const float*)d_in[0];
    const float* rw  = (const float*)d_in[1];
    const float* gns = (const float*)d_in[2];
    const float* gnb = (const float*)d_in[3];
    const float* w1  = (const float*)d_in[4];
    const float* b1  = (const float*)d_in[5];
    const float* w2  = (const float*)d_in[6];
    const float* b2  = (const float*)d_in[7];
    const float* fw  = (const float*)d_in[8];
    float* out = (float*)d_out;

    float* ws    = (float*)d_ws;
    float* sA    = ws;                               // 512
    float* sB    = sA + 512;
    float* wef   = sB + 512;
    float* part  = wef + 512;                        // 1600*128 = 204800
    float* abuf  = part + 204800;                    // 204800
    short* aPack = (short*)(abuf + 204800);          // 16384 shorts (32 KB)
    unsigned short* y1 = (unsigned short*)(aPack + 16384);  // 13,107,200 ushorts NHWC

    hipLaunchKernelGGL(k_pack,  dim3(8),           dim3(256), 0, stream, rw, aPack);
    hipLaunchKernelGGL(k_rmfma, dim3(1600),        dim3(256), 0, stream, x, aPack, y1, part);
    hipLaunchKernelGGL(k_gate,  dim3(1),           dim3(512), 0, stream,
                       part, gns, gnb, w1, b1, w2, b2, fw, sA, sB, wef);
    hipLaunchKernelGGL(k_sten,  dim3(10, 40, 8),   dim3(256), 0, stream, y1, sA, sB, wef, abuf);
    hipLaunchKernelGGL(k_apply, dim3(25, 256, 8),  dim3(256), 0, stream, x, abuf, out);
}